// Round 14
// baseline (280.305 us; speedup 1.0000x reference)
//
#include <hip/hip_runtime.h>
#include <hip/hip_fp16.h>
#include <math.h>

// T=1024 time steps, S=512 sequences, D=32 features, K=64 states
#define TT 1024
#define SS 512
#define DD 32
#define KK 64

#define LOG2PI_F 1.8378770664093453f
#define L2E_F    1.4426950408889634f
#define LN2_F    0.6931471805599453f

// MFMA recursion (r13 verbatim): 16 sequences/wave, NSEG=32 segments.
#define QSEQ 16
#define NSEG 32
#define SEGLEN (TT / NSEG)   // 32
#define BURN 64

// Workspace layout (d_ws):
//   [0, 64MB)        : p''[T,S,K] fp16 (max-shifted emission probs)
//   [+0, +32KB)      : float mpart[8192]  (log2-domain max sums)
//   [+32KB, +64KB)   : float seq_logd[NSEG*S]
//   [+96KB, +17.4KB) : float tables[64*68] (m[32], w'[32], C2, pad)
#define PBUF_BYTES ((size_t)TT * SS * KK * 2)
#define NWAVES 8192                  // one wave per 64 items = T*S/64
#define EM_TBL 68                    // floats per state in the prep table
#define LP_STR 65                    // LDS logp row stride (2-way banks, free)

typedef float v2f __attribute__((ext_vector_type(2)));
typedef float f32x4 __attribute__((ext_vector_type(4)));
typedef _Float16 h8 __attribute__((ext_vector_type(8)));

__device__ __forceinline__ v2f fma2(v2f a, v2f b, v2f c) {
#if __has_builtin(__builtin_elementwise_fma)
    return __builtin_elementwise_fma(a, b, c);
#else
    v2f r; r.x = fmaf(a.x, b.x, c.x); r.y = fmaf(a.y, b.y, c.y); return r;
#endif
}

__device__ __forceinline__ float fast_exp2(float x) {
#if __has_builtin(__builtin_amdgcn_exp2f)
    return __builtin_amdgcn_exp2f(x);       // v_exp_f32 (native base-2)
#else
    return __expf(x * LN2_F);
#endif
}

// ---------------------------------------------------------------------------
// DPP reductions.
template <int CTRL, int RMASK>
__device__ __forceinline__ float dpp_add_bc(float x) {
    int t = __builtin_amdgcn_update_dpp(0, __float_as_int(x), CTRL, RMASK, 0xf, true);
    return x + __int_as_float(t);
}
__device__ __forceinline__ float wave_reduce_sum(float x) {
    x = dpp_add_bc<0x111, 0xf>(x);   // row_shr:1
    x = dpp_add_bc<0x112, 0xf>(x);   // row_shr:2
    x = dpp_add_bc<0x114, 0xf>(x);   // row_shr:4
    x = dpp_add_bc<0x118, 0xf>(x);   // row_shr:8
    x = dpp_add_bc<0x142, 0xa>(x);   // row_bcast:15 into rows 1,3
    x = dpp_add_bc<0x143, 0xc>(x);   // row_bcast:31 into rows 2,3
    return __int_as_float(__builtin_amdgcn_readlane(__float_as_int(x), 63));
}
// 16-lane row sum via row_ror rotate-reduce (all 16 lanes end with the total).
template <int N>
__device__ __forceinline__ float dpp_ror_add(float x) {
    int xi = __float_as_int(x);
    int t = __builtin_amdgcn_update_dpp(xi, xi, 0x120 + N, 0xf, 0xf, false);
    return x + __int_as_float(t);
}
__device__ __forceinline__ float rowsum16(float x) {
    x = dpp_ror_add<8>(x);
    x = dpp_ror_add<4>(x);
    x = dpp_ror_add<2>(x);
    x = dpp_ror_add<1>(x);
    return x;
}

// ---------------------------------------------------------------------------
// Prep: per-state constants for the lane=item emission.
// tables[k*68 + 0..31] = mean, [32..63] = w' = -0.5*log2e/covar,
// [64] = C2 = -0.5*log2e*(D*log2pi + sum log covar).
__global__ __launch_bounds__(64) void prep_kernel(
    const float* __restrict__ means, const float* __restrict__ covars,
    float* __restrict__ tables)
{
    const int k = threadIdx.x;
    float acc = DD * LOG2PI_F;
    for (int d = 0; d < DD; ++d) {
        float c = covars[k * DD + d];
        tables[k * EM_TBL + d]      = means[k * DD + d];
        tables[k * EM_TBL + 32 + d] = -0.5f * L2E_F / c;
        acc += __logf(c);
    }
    tables[k * EM_TBL + 64] = -0.5f * L2E_F * acc;
}

// ---------------------------------------------------------------------------
// Emission, lane = item: one wave per 64 consecutive (t,s) items.
//
// r4-r13 plateau (~115us across 5 variants): lane=state keeps 64 VGPRs of
// per-lane constants live, and the backend ALWAYS injects per-item reloads
// (VALUBusy x dur shows ~3x instruction bloat in every variant). Here the
// register story is minimal by construction:
//  - x: 32 VGPRs per lane (own item), loaded once, coalesced 128B/lane.
//  - per-state constants: wave-uniform broadcast VMEM loads from the prep
//    table (17 KB, L1/L2-hot across all 8192 waves); transient only.
//  - pass 1: logp2[item][k] -> LDS tile (stride-65 rows: (l+k)%32 banks,
//    2-way = free both for writes and reads).
//  - pass 2: per-item max is a PURE per-lane fmax tree (the 6x64 DPP-max
//    chains per wave disappear); exp2 + f16x8 packed 16B stores.
// mpart[wv] = sum over the wave's 64 items of mx2 (log2 units).
__global__ __launch_bounds__(64)
__attribute__((amdgpu_waves_per_eu(1, 2)))
void emission_kernel(
    const float* __restrict__ data,      // [T,S,D]
    const float* __restrict__ tables,    // [64*68]
    __half* __restrict__ pbuf,           // [T,S,K]
    float* __restrict__ mpart)           // [NWAVES], log2 units
{
    const int l  = threadIdx.x;
    const int wv = blockIdx.x;
    const int item = wv * 64 + l;

    __shared__ float lp[64 * LP_STR];    // 16.6 KB

    // x for this lane's item: 16 v2f = 32 VGPRs.
    v2f xv[DD / 2];
    {
        const float4* xp = (const float4*)(data + (size_t)item * DD);
#pragma unroll
        for (int j = 0; j < DD / 4; ++j) {
            float4 x = xp[j];
            v2f a; a.x = x.x; a.y = x.y;
            v2f b; b.x = x.z; b.y = x.w;
            xv[2 * j] = a; xv[2 * j + 1] = b;
        }
    }

    // Pass 1: logp2 for all 64 states.
    for (int k = 0; k < KK; ++k) {
        const float* tb = tables + k * EM_TBL;       // wave-uniform
        const float4* mq = (const float4*)tb;
        const float4* wq = (const float4*)(tb + 32);
        float C2 = tb[64];
        v2f q0 = {0.0f, 0.0f}, q1 = {0.0f, 0.0f};
        v2f q2 = {0.0f, 0.0f}, q3 = {0.0f, 0.0f};
        q0.x = C2;
#pragma unroll
        for (int j = 0; j < DD / 8; ++j) {           // 8 dims per iter
            float4 mv0 = mq[2 * j], mv1 = mq[2 * j + 1];
            float4 wv0 = wq[2 * j], wv1 = wq[2 * j + 1];
            v2f m01; m01.x = mv0.x; m01.y = mv0.y;
            v2f m23; m23.x = mv0.z; m23.y = mv0.w;
            v2f m45; m45.x = mv1.x; m45.y = mv1.y;
            v2f m67; m67.x = mv1.z; m67.y = mv1.w;
            v2f w01; w01.x = wv0.x; w01.y = wv0.y;
            v2f w23; w23.x = wv0.z; w23.y = wv0.w;
            v2f w45; w45.x = wv1.x; w45.y = wv1.y;
            v2f w67; w67.x = wv1.z; w67.y = wv1.w;
            v2f t0 = xv[4 * j]     - m01;
            v2f t1 = xv[4 * j + 1] - m23;
            v2f t2 = xv[4 * j + 2] - m45;
            v2f t3 = xv[4 * j + 3] - m67;
            q0 = fma2(w01 * t0, t0, q0);
            q1 = fma2(w23 * t1, t1, q1);
            q2 = fma2(w45 * t2, t2, q2);
            q3 = fma2(w67 * t3, t3, q3);
        }
        v2f s = (q0 + q1) + (q2 + q3);
        lp[l * LP_STR + k] = s.x + s.y;
    }
    __builtin_amdgcn_wave_barrier();     // single wave: ordering fence

    // Pass 2a: per-item max over 64 states (4 ILP chains, pure per-lane).
    const float* row = lp + l * LP_STR;
    float m0 = row[0], m1 = row[1], m2 = row[2], m3 = row[3];
#pragma unroll
    for (int j = 4; j < KK; j += 4) {
        m0 = fmaxf(m0, row[j]);
        m1 = fmaxf(m1, row[j + 1]);
        m2 = fmaxf(m2, row[j + 2]);
        m3 = fmaxf(m3, row[j + 3]);
    }
    const float mx2 = fmaxf(fmaxf(m0, m1), fmaxf(m2, m3));

    // Pass 2b: p'' = exp2(logp2 - mx2) -> f16, 8 chunks x 16B stores.
    __half* pb = pbuf + (size_t)item * KK;           // 128B-aligned
#pragma unroll
    for (int c = 0; c < 8; ++c) {
        unsigned int out[4];
#pragma unroll
        for (int e = 0; e < 4; ++e) {
            float e0 = fast_exp2(row[c * 8 + 2 * e]     - mx2);
            float e1 = fast_exp2(row[c * 8 + 2 * e + 1] - mx2);
            __half2 h = __halves2half2(__float2half(e0), __float2half(e1));
            out[e] = *(unsigned int*)&h;
        }
        *(float4*)(pb + c * 8) = *(float4*)out;
    }

    // mpart: sum of the wave's 64 item-maxes (one DPP reduce per wave).
    float ms = wave_reduce_sum(mx2);
    if (l == 0) mpart[wv] = ms;
}

// ---------------------------------------------------------------------------
// MFMA forward recursion (r13 verbatim): one wave = 16 sequences x segment.
#define RSTR 72   // padded LDS row stride in halfs

__global__ __launch_bounds__(64)
__attribute__((amdgpu_waves_per_eu(1, 1)))
void hmm_mfma(
    const __half* __restrict__ pbuf,     // [T,S,K] f16 max-shifted probs
    const float* __restrict__ initial,   // [K]
    const float* __restrict__ trans,     // [K,K]
    float* __restrict__ out_alpha,       // [S,K]
    float* __restrict__ seq_logd)        // [NSEG*S]
{
    const int lane = threadIdx.x;
    const int col  = lane & 15;
    const int grp  = lane >> 4;
    const int s0   = blockIdx.x * QSEQ;
    const int seg  = blockIdx.y;

    const int emit_from = seg * SEGLEN;
    int t0 = emit_from - BURN; if (t0 < 0) t0 = 0;
    const int nsteps = (emit_from - t0) + SEGLEN;

    h8 bf[2][4];
#pragma unroll
    for (int kc = 0; kc < 2; ++kc)
#pragma unroll
        for (int nt = 0; nt < 4; ++nt) {
            h8 v;
#pragma unroll
            for (int e = 0; e < 8; ++e) {
                int j = kc * 32 + grp * 8 + e;
                v[e] = (_Float16)trans[j * KK + nt * 16 + col];
            }
            bf[kc][nt] = v;
        }

    float init_c[4];
#pragma unroll
    for (int nt = 0; nt < 4; ++nt)
        init_c[nt] = (t0 == 0) ? initial[nt * 16 + col] : 1.0f;

    __shared__ __align__(16) _Float16 ash[QSEQ * RSTR];
    __shared__ __align__(16) _Float16 plds[2][4 * QSEQ * RSTR];

    float4 pr[8];
#define XLOAD(TB)                                                             \
    {                                                                         \
        const float4* src = (const float4*)(pbuf +                            \
            (((size_t)((TB) + grp)) * SS + s0 + col) * KK);                   \
        _Pragma("unroll")                                                     \
        for (int e = 0; e < 8; ++e) pr[e] = src[e];                           \
    }
#define XWRITE(BUF)                                                           \
    {                                                                         \
        float4* dst = (float4*)(&plds[BUF][(grp * 16 + col) * RSTR]);         \
        _Pragma("unroll")                                                     \
        for (int e = 0; e < 8; ++e) dst[e] = pr[e];                           \
    }

    XLOAD(t0);
    XWRITE(0);
    __builtin_amdgcn_wave_barrier();

    h8 a0, a1;
    float ld[4] = {0.0f, 0.0f, 0.0f, 0.0f};
    int cur = 0;

    for (int g = 0; g < nsteps / 4; ++g) {
        const int tbase = t0 + 4 * g;
        int tb_next = tbase + 4;
        if (tb_next > TT - 4) tb_next = TT - 4;
        XLOAD(tb_next);

        const _Float16* pc_base = &plds[cur][0];
#pragma unroll
        for (int st = 0; st < 4; ++st) {
            const int t = tbase + st;
            f32x4 c[4];
            if (g == 0 && st == 0) {
#pragma unroll
                for (int nt = 0; nt < 4; ++nt) {
                    f32x4 z = {init_c[nt], init_c[nt], init_c[nt], init_c[nt]};
                    c[nt] = z;
                }
            } else {
                f32x4 z = {0.0f, 0.0f, 0.0f, 0.0f};
#pragma unroll
                for (int nt = 0; nt < 4; ++nt) {
                    c[nt] = __builtin_amdgcn_mfma_f32_16x16x32_f16(
                        a0, bf[0][nt], z, 0, 0, 0);
                    c[nt] = __builtin_amdgcn_mfma_f32_16x16x32_f16(
                        a1, bf[1][nt], c[nt], 0, 0, 0);
                }
            }

            float av[4][4];
            float pden[4] = {0.0f, 0.0f, 0.0f, 0.0f};
#pragma unroll
            for (int nt = 0; nt < 4; ++nt)
#pragma unroll
                for (int j = 0; j < 4; ++j) {
                    float pcv = (float)pc_base[
                        (st * 16 + grp * 4 + j) * RSTR + nt * 16 + col];
                    float v = c[nt][j] * pcv;
                    av[nt][j] = v;
                    pden[j] += v;
                }

            float r[4];
#pragma unroll
            for (int j = 0; j < 4; ++j) {
                float den = rowsum16(pden[j]);
                if (t >= emit_from) ld[j] += __logf(den);
                r[j] = __builtin_amdgcn_rcpf(den);
            }

#pragma unroll
            for (int nt = 0; nt < 4; ++nt)
#pragma unroll
                for (int j = 0; j < 4; ++j)
                    ash[(grp * 4 + j) * RSTR + nt * 16 + col] =
                        (_Float16)(av[nt][j] * r[j]);
            __builtin_amdgcn_wave_barrier();
            a0 = *(const h8*)(ash + col * RSTR + grp * 8);
            a1 = *(const h8*)(ash + col * RSTR + 32 + grp * 8);
            __builtin_amdgcn_wave_barrier();
        }

        XWRITE(cur ^ 1);
        __builtin_amdgcn_wave_barrier();
        cur ^= 1;
    }
#undef XLOAD
#undef XWRITE

    if (seg == NSEG - 1) {
#pragma unroll
        for (int nt = 0; nt < 4; ++nt)
#pragma unroll
            for (int j = 0; j < 4; ++j)
                out_alpha[(size_t)(s0 + grp * 4 + j) * KK + nt * 16 + col] =
                    (float)ash[(grp * 4 + j) * RSTR + nt * 16 + col];
    }
    if (col == 0) {
#pragma unroll
        for (int j = 0; j < 4; ++j)
            seq_logd[seg * SS + s0 + grp * 4 + j] = ld[j];
    }
}

// ---------------------------------------------------------------------------
// nll = -( sum seq_logd + ln2 * sum mpart )   (mpart is log2-domain)
__global__ __launch_bounds__(256) void finalize(
    const float* __restrict__ seq_logd, const float* __restrict__ mpart,
    float* __restrict__ out_nll)
{
    float v = 0.0f;
    for (int j = threadIdx.x; j < NWAVES; j += 256) v += mpart[j] * LN2_F;
    for (int j = threadIdx.x; j < NSEG * SS; j += 256) v += seq_logd[j];
#pragma unroll
    for (int off = 32; off > 0; off >>= 1)
        v += __shfl_xor(v, off, 64);
    __shared__ float sh[4];
    if ((threadIdx.x & 63) == 0) sh[threadIdx.x >> 6] = v;
    __syncthreads();
    if (threadIdx.x == 0) {
        double total = ((double)sh[0] + sh[1]) + ((double)sh[2] + sh[3]);
        out_nll[0] = (float)(-total);
    }
}

extern "C" void kernel_launch(void* const* d_in, const int* in_sizes, int n_in,
                              void* d_out, int out_size, void* d_ws, size_t ws_size,
                              hipStream_t stream) {
    const float* data    = (const float*)d_in[0];  // [T,S,D]
    const float* initial = (const float*)d_in[1];  // [K]
    const float* trans   = (const float*)d_in[2];  // [K,K]
    const float* means   = (const float*)d_in[3];  // [K,D]
    const float* covars  = (const float*)d_in[4];  // [K,D]

    float* out_alpha = (float*)d_out;                    // [S,K]
    float* out_nll   = (float*)d_out + (size_t)SS * KK;  // 1 float

    __half* pbuf     = (__half*)d_ws;
    float*  mpart    = (float*)((char*)d_ws + PBUF_BYTES);
    float*  seq_logd = (float*)((char*)d_ws + PBUF_BYTES + NWAVES * sizeof(float));
    float*  tables   = (float*)((char*)d_ws + PBUF_BYTES + NWAVES * sizeof(float)
                                + NSEG * SS * sizeof(float));

    prep_kernel<<<1, 64, 0, stream>>>(means, covars, tables);
    emission_kernel<<<NWAVES, 64, 0, stream>>>(data, tables, pbuf, mpart);
    hmm_mfma<<<dim3(SS / QSEQ, NSEG), 64, 0, stream>>>(
        pbuf, initial, trans, out_alpha, seq_logd);
    finalize<<<1, 256, 0, stream>>>(seq_logd, mpart, out_nll);
}